// Round 15
// baseline (223.638 us; speedup 1.0000x reference)
//
#include <hip/hip_runtime.h>
#include <math.h>

#define INPUT_DIM 128
#define OUT_DIM 128
#define NUM_GAUSS 20
#define NH 16
#define BM 64      // bonds per block in bond_proj
#define MAXT 16
#define WPB 4      // waves per block in attn_wave (2 segments per wave)
#define SCALE 0.35355339059327373f

// W_key/W_value row layout: [0:128) h_bond(kj), [128:148) r_kj, [148:168) r_ji, [168:181) a_feat

static __device__ __forceinline__ void wave_lds_fence() {
    __asm__ volatile("s_waitcnt lgkmcnt(0)" ::: "memory");
    __builtin_amdgcn_wave_barrier();
}

// R10-proven register-tiled GEMM + fused RBF staging (R6-proven).
// block = 64 bonds x 128 dims; thread = 8 bonds x 4 dims x {K,V,Q,E0}.
__global__ __launch_bounds__(256, 3) void bond_proj_kernel(
    const float* __restrict__ h_bond,
    const float* __restrict__ pos,
    const int*   __restrict__ bond_index,
    const float* __restrict__ Wk,
    const float* __restrict__ Wv,
    const float* __restrict__ Wq,
    const float* __restrict__ We0,
    float* __restrict__ r_out,
    float* __restrict__ KB,
    float* __restrict__ VB,
    float* __restrict__ QE,
    int E)
{
    __shared__ float As[BM * 148];
    const int tid = threadIdx.x;
    const int e0 = blockIdx.x * BM;

    // stage h (64x128)
    for (int i = tid; i < BM * 32; i += 256) {
        int e = i >> 5, c = (i & 31) << 2;
        float4 v = make_float4(0.f, 0.f, 0.f, 0.f);
        if (e0 + e < E) v = *(const float4*)&h_bond[(size_t)(e0 + e) * INPUT_DIM + c];
        float* dst = &As[e * 148 + c];
        dst[0] = v.x; dst[1] = v.y; dst[2] = v.z; dst[3] = v.w;
    }
    // stage r (64x20), computed inline (rbf fused); also write r_feat for attn
    {
        const float step = 10.f / (NUM_GAUSS - 1);
        const float coeff = -0.5f / (step * step);
        for (int i = tid; i < BM * NUM_GAUSS; i += 256) {
            int e = i / NUM_GAUSS, g = i % NUM_GAUSS;
            int ge = e0 + e;
            float rv = 0.f;
            if (ge < E) {
                int jrow = bond_index[ge];
                int icol = bond_index[E + ge];
                float dx = pos[icol*3+0] - pos[jrow*3+0];
                float dy = pos[icol*3+1] - pos[jrow*3+1];
                float dz = pos[icol*3+2] - pos[jrow*3+2];
                float dist = sqrtf(dx*dx + dy*dy + dz*dz);
                float t = dist - g * step;
                rv = __expf(coeff * t * t);
                r_out[(size_t)ge * NUM_GAUSS + g] = rv;
            }
            As[e * 148 + 128 + g] = rv;
        }
    }
    __syncthreads();

    const int em = tid >> 5;          // bond group: bonds em*8 .. em*8+7
    const int dn = (tid & 31) << 2;   // dim group: dims dn .. dn+3
    const float* AsB = &As[em * 8 * 148];

    float aK[8][4], aV[8][4], aQ[8][4], aE[8][4];
    #pragma unroll
    for (int m = 0; m < 8; ++m)
        #pragma unroll
        for (int j = 0; j < 4; ++j) { aK[m][j]=0.f; aV[m][j]=0.f; aQ[m][j]=0.f; aE[m][j]=0.f; }

    #pragma unroll 2
    for (int c = 0; c < 128; ++c) {
        float4 wk = *(const float4*)&Wk[c * OUT_DIM + dn];
        float4 wv = *(const float4*)&Wv[c * OUT_DIM + dn];
        float4 wq = *(const float4*)&Wq[c * OUT_DIM + dn];
        #pragma unroll
        for (int m = 0; m < 8; ++m) {
            float a = AsB[m * 148 + c];      // wave-broadcast LDS read
            aK[m][0] = fmaf(a, wk.x, aK[m][0]); aK[m][1] = fmaf(a, wk.y, aK[m][1]);
            aK[m][2] = fmaf(a, wk.z, aK[m][2]); aK[m][3] = fmaf(a, wk.w, aK[m][3]);
            aV[m][0] = fmaf(a, wv.x, aV[m][0]); aV[m][1] = fmaf(a, wv.y, aV[m][1]);
            aV[m][2] = fmaf(a, wv.z, aV[m][2]); aV[m][3] = fmaf(a, wv.w, aV[m][3]);
            aQ[m][0] = fmaf(a, wq.x, aQ[m][0]); aQ[m][1] = fmaf(a, wq.y, aQ[m][1]);
            aQ[m][2] = fmaf(a, wq.z, aQ[m][2]); aQ[m][3] = fmaf(a, wq.w, aQ[m][3]);
        }
    }
    #pragma unroll 2
    for (int g = 0; g < 20; ++g) {
        float4 wk = *(const float4*)&Wk[(INPUT_DIM + g) * OUT_DIM + dn];
        float4 wv = *(const float4*)&Wv[(INPUT_DIM + g) * OUT_DIM + dn];
        float4 w0 = *(const float4*)&We0[g * OUT_DIM + dn];
        #pragma unroll
        for (int m = 0; m < 8; ++m) {
            float a = AsB[m * 148 + 128 + g];
            aK[m][0] = fmaf(a, wk.x, aK[m][0]); aK[m][1] = fmaf(a, wk.y, aK[m][1]);
            aK[m][2] = fmaf(a, wk.z, aK[m][2]); aK[m][3] = fmaf(a, wk.w, aK[m][3]);
            aV[m][0] = fmaf(a, wv.x, aV[m][0]); aV[m][1] = fmaf(a, wv.y, aV[m][1]);
            aV[m][2] = fmaf(a, wv.z, aV[m][2]); aV[m][3] = fmaf(a, wv.w, aV[m][3]);
            aE[m][0] = fmaf(a, w0.x, aE[m][0]); aE[m][1] = fmaf(a, w0.y, aE[m][1]);
            aE[m][2] = fmaf(a, w0.z, aE[m][2]); aE[m][3] = fmaf(a, w0.w, aE[m][3]);
        }
    }

    #pragma unroll
    for (int m = 0; m < 8; ++m) {
        int e = e0 + em * 8 + m;
        if (e < E) {
            *(float4*)&KB[(size_t)e * OUT_DIM + dn] =
                make_float4(aK[m][0], aK[m][1], aK[m][2], aK[m][3]);
            *(float4*)&VB[(size_t)e * OUT_DIM + dn] =
                make_float4(aV[m][0], aV[m][1], aV[m][2], aV[m][3]);
            *(float4*)&QE[(size_t)e * OUT_DIM + dn] =
                make_float4(aQ[m][0] * tanhf(aE[m][0]), aQ[m][1] * tanhf(aE[m][1]),
                            aQ[m][2] * tanhf(aE[m][2]), aQ[m][3] * tanhf(aE[m][3]));
        }
    }
}

// 2 segments per wave: lane l = (sg = l>>5, s = l&31). Lane owns dims 4s..4s+3
// of segment e = base + sg. Head h = s>>1 spans a 2-lane group (a = s&1).
// KV rows are contiguous: kj = jj*12 + t (valid when T == E*12).
// r-only projections (was redge_kernel) computed inline from r_feat + weights.
__global__ __launch_bounds__(256) void attn_wave_kernel(
    const float* __restrict__ pos,
    const int*   __restrict__ idx_i,
    const int*   __restrict__ idx_j,
    const int*   __restrict__ idx_k,
    const float* __restrict__ Wk,
    const float* __restrict__ Wv,
    const float* __restrict__ We1,
    const float* __restrict__ r_feat,
    const float* __restrict__ KB,
    const float* __restrict__ VB,
    const float* __restrict__ QE,
    float* __restrict__ out,
    int E)
{
    __shared__ float afL[WPB][2][12][13];

    // bijective XCD-aware swizzle (m204)
    unsigned bid = blockIdx.x, nwg = gridDim.x;
    unsigned qq = nwg >> 3, rr = nwg & 7, xc = bid & 7, rest = bid >> 3;
    unsigned swz = (xc < rr ? xc * (qq + 1) : rr * (qq + 1) + (xc - rr) * qq) + rest;

    const int l = threadIdx.x & 63;
    const int wvn = __builtin_amdgcn_readfirstlane(threadIdx.x >> 6);
    const int sg = l >> 5;          // which of the wave's 2 segments
    const int s  = l & 31;          // lane within segment
    const int e = (int)swz * (WPB * 2) + wvn * 2 + sg;
    if (e >= E) return;
    const int h = s >> 1;
    const int a = s & 1;
    const int d4 = 4 * s;           // dims d4..d4+3

    const int ii = idx_i[(size_t)e * 12];
    const int jj = idx_j[(size_t)e * 12];
    const size_t kjb = (size_t)jj * 12;   // contiguous KV block base row

    const float4 qe4 = *(const float4*)&QE[(size_t)e * OUT_DIM + d4];

    // ---- r-only projections inline (replaces redge kernel) ----
    // EA1 = tanh(r@We1), RV2 = r@Wv[148:168], RK2 = r@Wk[148:168]
    float a1x=0.f,a1y=0.f,a1z=0.f,a1w=0.f;
    float arx=0.f,ary=0.f,arz=0.f,arw=0.f;
    float avx=0.f,avy=0.f,avz=0.f,avw=0.f;
    {
        const float* rp = &r_feat[(size_t)e * NUM_GAUSS];
        #pragma unroll
        for (int g = 0; g < NUM_GAUSS; ++g) {
            float rg = rp[g];   // half-wave-uniform, L1-broadcast
            float4 w1  = *(const float4*)&We1[g * OUT_DIM + d4];
            float4 wkr = *(const float4*)&Wk[(148 + g) * OUT_DIM + d4];
            float4 wvr = *(const float4*)&Wv[(148 + g) * OUT_DIM + d4];
            a1x = fmaf(rg, w1.x, a1x); a1y = fmaf(rg, w1.y, a1y);
            a1z = fmaf(rg, w1.z, a1z); a1w = fmaf(rg, w1.w, a1w);
            arx = fmaf(rg, wkr.x, arx); ary = fmaf(rg, wkr.y, ary);
            arz = fmaf(rg, wkr.z, arz); arw = fmaf(rg, wkr.w, arw);
            avx = fmaf(rg, wvr.x, avx); avy = fmaf(rg, wvr.y, avy);
            avz = fmaf(rg, wvr.z, avz); avw = fmaf(rg, wvr.w, avw);
        }
    }
    float4 ea4 = make_float4(tanhf(a1x), tanhf(a1y), tanhf(a1z), tanhf(a1w));
    float4 erv4 = make_float4(ea4.x * avx, ea4.y * avy, ea4.z * avz, ea4.w * avw);
    float qrk2 = qe4.x*arx + qe4.y*ary + qe4.z*arz + qe4.w*arw;
    qrk2 += __shfl_xor(qrk2, 1);    // per-head dot8 across lane pair

    // ---- triplet geometry (s < 12 lanes of each half) -> afL ----
    const float pix = pos[ii*3+0], piy = pos[ii*3+1], piz = pos[ii*3+2];
    const float jx = pos[jj*3+0]-pix, jy = pos[jj*3+1]-piy, jz = pos[jj*3+2]-piz;
    if (s < 12) {
        int kk = idx_k[(size_t)e * 12 + s];
        float kx = pos[kk*3+0]-pix, ky = pos[kk*3+1]-piy, kz = pos[kk*3+2]-piz;
        float aa = jx*kx + jy*ky + jz*kz;
        float cx = jy*kz - jz*ky, cy = jz*kx - jx*kz, cz = jx*ky - jy*kx;
        float bb = sqrtf(cx*cx + cy*cy + cz*cz);
        float ang = atan2f(bb, aa);
        float af0[13];
        af0[0] = ang;
        const float fr[6] = {1.f, 2.f, 3.f, 1.f, 0.5f, 1.f/3.f};
        #pragma unroll
        for (int q = 0; q < 6; ++q)
            __sincosf(ang * fr[q], &af0[1+q], &af0[7+q]);
        #pragma unroll
        for (int c = 0; c < 13; ++c) afL[wvn][sg][s][c] = af0[c];
    }

    // ---- qwk[c] = per-head dot8(QE, WkA[c]) : dot4 in-lane + 1 DPP ----
    float qwk[13];
    #pragma unroll
    for (int c = 0; c < 13; ++c) {
        float4 w = *(const float4*)&Wk[(168 + c) * OUT_DIM + d4];
        float p = qe4.x*w.x + qe4.y*w.y + qe4.z*w.z + qe4.w*w.w;
        p += __shfl_xor(p, 1);
        qwk[c] = p;
    }

    // ---- QK bond part for all 12 t; lane keeps t with (t&1)==a ----
    float qk6[6];
    #pragma unroll
    for (int t = 0; t < 12; ++t) {
        float4 kb = *(const float4*)&KB[(kjb + t) * OUT_DIM + d4];
        float v = qe4.x*kb.x + qe4.y*kb.y + qe4.z*kb.z + qe4.w*kb.w;
        v += __shfl_xor(v, 1);
        if ((t & 1) == a) qk6[t >> 1] = v;
    }

    wave_lds_fence();   // af ready

    // ---- angular part for own 6 t's + combine ----
    float lg[6];
    #pragma unroll
    for (int q = 0; q < 6; ++q) {
        int t = 2*q + a;
        float ang = 0.f;
        #pragma unroll
        for (int c = 0; c < 13; ++c) ang = fmaf(afL[wvn][sg][t][c], qwk[c], ang);
        lg[q] = (qk6[q] + ang + qrk2) * SCALE;
    }

    // ---- softmax over 12 within the 2-lane head group ----
    float m = lg[0];
    #pragma unroll
    for (int q = 1; q < 6; ++q) m = fmaxf(m, lg[q]);
    m = fmaxf(m, __shfl_xor(m, 1));
    float ex[6], ss = 0.f;
    #pragma unroll
    for (int q = 0; q < 6; ++q) { ex[q] = __expf(lg[q] - m); ss += ex[q]; }
    ss += __shfl_xor(ss, 1);
    float inv = 1.f / (ss + 1e-16f);
    float al[6], alp[6];
    #pragma unroll
    for (int q = 0; q < 6; ++q) { al[q] = ex[q] * inv; alp[q] = __shfl_xor(al[q], 1); }
    float Sh = ss * inv;

    // ---- waf[c] = sum_t alpha[t][h]*af[t][c] (own 6 t + 1 DPP) ----
    float waf[13];
    #pragma unroll
    for (int c = 0; c < 13; ++c) {
        float wp = 0.f;
        #pragma unroll
        for (int q = 0; q < 6; ++q) wp = fmaf(al[q], afL[wvn][sg][2*q + a][c], wp);
        wp += __shfl_xor(wp, 1);
        waf[c] = wp;
    }

    // ---- value accumulation over all 12 t (alpha via partner regs) ----
    float ac0 = 0.f, ac1 = 0.f, ac2 = 0.f, ac3 = 0.f;
    #pragma unroll
    for (int t = 0; t < 12; ++t) {
        float4 vb = *(const float4*)&VB[(kjb + t) * OUT_DIM + d4];
        float at = ((t & 1) == a) ? al[t >> 1] : alp[t >> 1];
        ac0 = fmaf(at, vb.x, ac0); ac1 = fmaf(at, vb.y, ac1);
        ac2 = fmaf(at, vb.z, ac2); ac3 = fmaf(at, vb.w, ac3);
    }

    // ---- angular value projection for this lane's 4 dims ----
    float vA0 = 0.f, vA1 = 0.f, vA2 = 0.f, vA3 = 0.f;
    #pragma unroll
    for (int c = 0; c < 13; ++c) {
        float4 w = *(const float4*)&Wv[(168 + c) * OUT_DIM + d4];
        vA0 = fmaf(waf[c], w.x, vA0); vA1 = fmaf(waf[c], w.y, vA1);
        vA2 = fmaf(waf[c], w.z, vA2); vA3 = fmaf(waf[c], w.w, vA3);
    }

    float4 o;
    o.x = ea4.x * (ac0 + vA0) + erv4.x * Sh;
    o.y = ea4.y * (ac1 + vA1) + erv4.y * Sh;
    o.z = ea4.z * (ac2 + vA2) + erv4.z * Sh;
    o.w = ea4.w * (ac3 + vA3) + erv4.w * Sh;
    *(float4*)&out[(size_t)e * OUT_DIM + d4] = o;
}

// ---------------- generic fallback (unused when T == E*12) ----------------
__global__ __launch_bounds__(128) void attn_generic_kernel(
    const float* __restrict__ pos,
    const int*   __restrict__ idx_i,
    const int*   __restrict__ idx_j,
    const int*   __restrict__ idx_k,
    const int*   __restrict__ idx_kj,
    const int*   __restrict__ idx_ji,
    const float* __restrict__ Wk,
    const float* __restrict__ Wv,
    const float* __restrict__ We1,
    const float* __restrict__ r_feat,
    const float* __restrict__ KB,
    const float* __restrict__ VB,
    const float* __restrict__ QE,
    float* __restrict__ out,
    int E, int T)
{
    __shared__ float rs[NUM_GAUSS];
    __shared__ float af[MAXT][13];
    __shared__ float logit[MAXT][NH];
    __shared__ float qwk[NH][13];
    __shared__ float waf[NH][13];
    __shared__ int   kjs[MAXT];
    __shared__ float qrk2s[NH];
    __shared__ float Shs[NH];

    const int e = blockIdx.x;
    const int d = threadIdx.x;
    const int h8 = d >> 3;

    int l = 0, hi = T;
    while (l < hi) { int mid = (l + hi) >> 1; if (idx_ji[mid] < e) l = mid + 1; else hi = mid; }
    int lo = l, c2 = 0;
    while (lo + c2 < T && c2 < MAXT && idx_ji[lo + c2] == e) ++c2;
    int cnt = c2;

    if (d < NUM_GAUSS) rs[d] = r_feat[(size_t)e * NUM_GAUSS + d];
    if (d < cnt) {
        int t = lo + d;
        kjs[d] = idx_kj[t];
        int ii = idx_i[t], jj = idx_j[t], kk = idx_k[t];
        float pix = pos[ii*3+0], piy = pos[ii*3+1], piz = pos[ii*3+2];
        float jx = pos[jj*3+0]-pix, jy = pos[jj*3+1]-piy, jz = pos[jj*3+2]-piz;
        float kx = pos[kk*3+0]-pix, ky = pos[kk*3+1]-piy, kz = pos[kk*3+2]-piz;
        float aa = jx*kx + jy*ky + jz*kz;
        float cx = jy*kz - jz*ky, cy = jz*kx - jx*kz, cz = jx*ky - jy*kx;
        float bb = sqrtf(cx*cx + cy*cy + cz*cz);
        float ang = atan2f(bb, aa);
        af[d][0] = ang;
        const float fr[6] = {1.f, 2.f, 3.f, 1.f, 0.5f, 1.f/3.f};
        #pragma unroll
        for (int q = 0; q < 6; ++q) {
            float s, cc;
            __sincosf(ang * fr[q], &s, &cc);
            af[d][1 + q] = s;
            af[d][7 + q] = cc;
        }
    }
    __syncthreads();

    const float qe = QE[(size_t)e * OUT_DIM + d];
    float s1 = 0.f, sk = 0.f, sv = 0.f;
    #pragma unroll
    for (int g = 0; g < NUM_GAUSS; ++g) {
        float rg = rs[g];
        s1 = fmaf(rg, We1[g * OUT_DIM + d], s1);
        sk = fmaf(rg, Wk[(148 + g) * OUT_DIM + d], sk);
        sv = fmaf(rg, Wv[(148 + g) * OUT_DIM + d], sv);
    }
    const float ea1 = tanhf(s1);
    const float rv2 = sv;

    {
        float v = qe * sk;
        v += __shfl_xor(v, 1, 8); v += __shfl_xor(v, 2, 8); v += __shfl_xor(v, 4, 8);
        if ((d & 7) == 0) qrk2s[h8] = v;
    }
    {
        float p[13];
        #pragma unroll
        for (int c = 0; c < 13; ++c) p[c] = qe * Wk[(168 + c) * OUT_DIM + d];
        #pragma unroll
        for (int c = 0; c < 13; ++c) {
            float v = p[c];
            v += __shfl_xor(v, 1, 8); v += __shfl_xor(v, 2, 8); v += __shfl_xor(v, 4, 8);
            if ((d & 7) == 0) qwk[h8][c] = v;
        }
    }
    for (int t = 0; t < cnt; ++t) {
        float lv = qe * KB[(size_t)kjs[t] * OUT_DIM + d];
        lv += __shfl_xor(lv, 1, 8); lv += __shfl_xor(lv, 2, 8); lv += __shfl_xor(lv, 4, 8);
        if ((d & 7) == 0) logit[t][h8] = lv;
    }
    __syncthreads();
    {
        const int hh = d & 15;
        for (int t = d >> 4; t < cnt; t += 8) {
            float s = 0.f;
            #pragma unroll
            for (int c = 0; c < 13; ++c) s = fmaf(af[t][c], qwk[hh][c], s);
            logit[t][hh] = (logit[t][hh] + s + qrk2s[hh]) * SCALE;
        }
    }
    __syncthreads();
    if (d < NH) {
        float m = -1e30f;
        for (int t = 0; t < cnt; ++t) m = fmaxf(m, logit[t][d]);
        float s = 0.f;
        for (int t = 0; t < cnt; ++t) { float ex = __expf(logit[t][d] - m); logit[t][d] = ex; s += ex; }
        float inv = 1.f / (s + 1e-16f);
        for (int t = 0; t < cnt; ++t) logit[t][d] *= inv;
        Shs[d] = s * inv;
    }
    __syncthreads();
    {
        const int hh = d & 15;
        int c = d >> 4;
        float w1 = 0.f;
        for (int t = 0; t < cnt; ++t) w1 = fmaf(logit[t][hh], af[t][c], w1);
        waf[hh][c] = w1;
        c += 8;
        if (c < 13) {
            float w2 = 0.f;
            for (int t = 0; t < cnt; ++t) w2 = fmaf(logit[t][hh], af[t][c], w2);
            waf[hh][c] = w2;
        }
    }
    __syncthreads();
    float vA = 0.f;
    #pragma unroll
    for (int c = 0; c < 13; ++c) vA = fmaf(waf[h8][c], Wv[(168 + c) * OUT_DIM + d], vA);
    float acc = 0.f;
    for (int t = 0; t < cnt; ++t)
        acc = fmaf(logit[t][h8], VB[(size_t)kjs[t] * OUT_DIM + d], acc);
    out[(size_t)e * OUT_DIM + d] = ea1 * (acc + vA + rv2 * Shs[h8]);
}

extern "C" void kernel_launch(void* const* d_in, const int* in_sizes, int n_in,
                              void* d_out, int out_size, void* d_ws, size_t ws_size,
                              hipStream_t stream) {
    const float* h_bond = (const float*)d_in[1];
    const float* pos    = (const float*)d_in[2];
    const int*   bidx   = (const int*)d_in[3];
    const int*   idx_i  = (const int*)d_in[4];
    const int*   idx_j  = (const int*)d_in[5];
    const int*   idx_k  = (const int*)d_in[6];
    const int*   idx_kj = (const int*)d_in[7];
    const int*   idx_ji = (const int*)d_in[8];
    const float* Wk     = (const float*)d_in[9];
    const float* Wv     = (const float*)d_in[10];
    const float* Wq     = (const float*)d_in[11];
    const float* We0    = (const float*)d_in[12];
    const float* We1    = (const float*)d_in[13];

    const int E = in_sizes[1] / INPUT_DIM;
    const int T = in_sizes[4];

    float* ws = (float*)d_ws;
    float* r_feat = ws;                               // E*20
    float* KB = r_feat + (size_t)E * NUM_GAUSS;       // E*128
    float* VB = KB + (size_t)E * OUT_DIM;             // E*128
    float* QE = VB + (size_t)E * OUT_DIM;             // E*128
    // total ws: E*(20 + 3*128)*4 B  (~79 MB for E=49152)

    bond_proj_kernel<<<(E + BM - 1) / BM, 256, 0, stream>>>(
        h_bond, pos, bidx, Wk, Wv, Wq, We0, r_feat, KB, VB, QE, E);

    if (T == E * 12) {
        const int segs_per_block = WPB * 2;
        attn_wave_kernel<<<(E + segs_per_block - 1) / segs_per_block, 64 * WPB, 0, stream>>>(
            pos, idx_i, idx_j, idx_k,
            Wk, Wv, We1, r_feat, KB, VB, QE, (float*)d_out, E);
    } else {
        attn_generic_kernel<<<E, 128, 0, stream>>>(
            pos, idx_i, idx_j, idx_k, idx_kj, idx_ji,
            Wk, Wv, We1, r_feat, KB, VB, QE, (float*)d_out, E, T);
    }
}

// Round 16
// 161.824 us; speedup vs baseline: 1.3820x; 1.3820x over previous
//
#include <hip/hip_runtime.h>
#include <math.h>

#define INPUT_DIM 128
#define OUT_DIM 128
#define NUM_GAUSS 20
#define NH 16
#define BM 64      // bonds per block in bond_proj / redge
#define MAXT 16
#define WPB 4      // waves per block in attn_wave (2 segments per wave)
#define SCALE 0.35355339059327373f

// W_key/W_value row layout: [0:128) h_bond(kj), [128:148) r_kj, [148:168) r_ji, [168:181) a_feat

static __device__ __forceinline__ void wave_lds_fence() {
    __asm__ volatile("s_waitcnt lgkmcnt(0)" ::: "memory");
    __builtin_amdgcn_wave_barrier();
}

// R10-proven register-tiled GEMM + fused RBF staging (R15-measured ~60us).
// block = 64 bonds x 128 dims; thread = 8 bonds x 4 dims x {K,V,Q,E0}.
__global__ __launch_bounds__(256, 3) void bond_proj_kernel(
    const float* __restrict__ h_bond,
    const float* __restrict__ pos,
    const int*   __restrict__ bond_index,
    const float* __restrict__ Wk,
    const float* __restrict__ Wv,
    const float* __restrict__ Wq,
    const float* __restrict__ We0,
    float* __restrict__ r_out,
    float* __restrict__ KB,
    float* __restrict__ VB,
    float* __restrict__ QE,
    int E)
{
    __shared__ float As[BM * 148];
    const int tid = threadIdx.x;
    const int e0 = blockIdx.x * BM;

    // stage h (64x128)
    for (int i = tid; i < BM * 32; i += 256) {
        int e = i >> 5, c = (i & 31) << 2;
        float4 v = make_float4(0.f, 0.f, 0.f, 0.f);
        if (e0 + e < E) v = *(const float4*)&h_bond[(size_t)(e0 + e) * INPUT_DIM + c];
        float* dst = &As[e * 148 + c];
        dst[0] = v.x; dst[1] = v.y; dst[2] = v.z; dst[3] = v.w;
    }
    // stage r (64x20), computed inline (rbf fused); also write r_feat for downstream
    {
        const float step = 10.f / (NUM_GAUSS - 1);
        const float coeff = -0.5f / (step * step);
        for (int i = tid; i < BM * NUM_GAUSS; i += 256) {
            int e = i / NUM_GAUSS, g = i % NUM_GAUSS;
            int ge = e0 + e;
            float rv = 0.f;
            if (ge < E) {
                int jrow = bond_index[ge];
                int icol = bond_index[E + ge];
                float dx = pos[icol*3+0] - pos[jrow*3+0];
                float dy = pos[icol*3+1] - pos[jrow*3+1];
                float dz = pos[icol*3+2] - pos[jrow*3+2];
                float dist = sqrtf(dx*dx + dy*dy + dz*dz);
                float t = dist - g * step;
                rv = __expf(coeff * t * t);
                r_out[(size_t)ge * NUM_GAUSS + g] = rv;
            }
            As[e * 148 + 128 + g] = rv;
        }
    }
    __syncthreads();

    const int em = tid >> 5;          // bond group: bonds em*8 .. em*8+7
    const int dn = (tid & 31) << 2;   // dim group: dims dn .. dn+3
    const float* AsB = &As[em * 8 * 148];

    float aK[8][4], aV[8][4], aQ[8][4], aE[8][4];
    #pragma unroll
    for (int m = 0; m < 8; ++m)
        #pragma unroll
        for (int j = 0; j < 4; ++j) { aK[m][j]=0.f; aV[m][j]=0.f; aQ[m][j]=0.f; aE[m][j]=0.f; }

    #pragma unroll 2
    for (int c = 0; c < 128; ++c) {
        float4 wk = *(const float4*)&Wk[c * OUT_DIM + dn];
        float4 wv = *(const float4*)&Wv[c * OUT_DIM + dn];
        float4 wq = *(const float4*)&Wq[c * OUT_DIM + dn];
        #pragma unroll
        for (int m = 0; m < 8; ++m) {
            float a = AsB[m * 148 + c];      // wave-broadcast LDS read
            aK[m][0] = fmaf(a, wk.x, aK[m][0]); aK[m][1] = fmaf(a, wk.y, aK[m][1]);
            aK[m][2] = fmaf(a, wk.z, aK[m][2]); aK[m][3] = fmaf(a, wk.w, aK[m][3]);
            aV[m][0] = fmaf(a, wv.x, aV[m][0]); aV[m][1] = fmaf(a, wv.y, aV[m][1]);
            aV[m][2] = fmaf(a, wv.z, aV[m][2]); aV[m][3] = fmaf(a, wv.w, aV[m][3]);
            aQ[m][0] = fmaf(a, wq.x, aQ[m][0]); aQ[m][1] = fmaf(a, wq.y, aQ[m][1]);
            aQ[m][2] = fmaf(a, wq.z, aQ[m][2]); aQ[m][3] = fmaf(a, wq.w, aQ[m][3]);
        }
    }
    #pragma unroll 2
    for (int g = 0; g < 20; ++g) {
        float4 wk = *(const float4*)&Wk[(INPUT_DIM + g) * OUT_DIM + dn];
        float4 wv = *(const float4*)&Wv[(INPUT_DIM + g) * OUT_DIM + dn];
        float4 w0 = *(const float4*)&We0[g * OUT_DIM + dn];
        #pragma unroll
        for (int m = 0; m < 8; ++m) {
            float a = AsB[m * 148 + 128 + g];
            aK[m][0] = fmaf(a, wk.x, aK[m][0]); aK[m][1] = fmaf(a, wk.y, aK[m][1]);
            aK[m][2] = fmaf(a, wk.z, aK[m][2]); aK[m][3] = fmaf(a, wk.w, aK[m][3]);
            aV[m][0] = fmaf(a, wv.x, aV[m][0]); aV[m][1] = fmaf(a, wv.y, aV[m][1]);
            aV[m][2] = fmaf(a, wv.z, aV[m][2]); aV[m][3] = fmaf(a, wv.w, aV[m][3]);
            aE[m][0] = fmaf(a, w0.x, aE[m][0]); aE[m][1] = fmaf(a, w0.y, aE[m][1]);
            aE[m][2] = fmaf(a, w0.z, aE[m][2]); aE[m][3] = fmaf(a, w0.w, aE[m][3]);
        }
    }

    #pragma unroll
    for (int m = 0; m < 8; ++m) {
        int e = e0 + em * 8 + m;
        if (e < E) {
            *(float4*)&KB[(size_t)e * OUT_DIM + dn] =
                make_float4(aK[m][0], aK[m][1], aK[m][2], aK[m][3]);
            *(float4*)&VB[(size_t)e * OUT_DIM + dn] =
                make_float4(aV[m][0], aV[m][1], aV[m][2], aV[m][3]);
            *(float4*)&QE[(size_t)e * OUT_DIM + dn] =
                make_float4(aQ[m][0] * tanhf(aE[m][0]), aQ[m][1] * tanhf(aE[m][1]),
                            aQ[m][2] * tanhf(aE[m][2]), aQ[m][3] * tanhf(aE[m][3]));
        }
    }
}

// r-only projections (K=20): EA1 = tanh(r@We1), ERV = EA1*(r@Wv[148:168]),
// QRK2[e][h] = dot_h(QE, r@Wk[148:168]).  (R10-proven, ~15us)
__global__ __launch_bounds__(256) void redge_kernel(
    const float* __restrict__ r_feat,
    const float* __restrict__ QE,
    const float* __restrict__ Wk,
    const float* __restrict__ Wv,
    const float* __restrict__ We1,
    float* __restrict__ EA1,
    float* __restrict__ ERV,
    float* __restrict__ QRK2,
    int E)
{
    __shared__ float Rs[BM][NUM_GAUSS];
    const int tid = threadIdx.x;
    const int e0 = blockIdx.x * BM;

    for (int i = tid; i < BM * 5; i += 256) {
        int e = i / 5, q = (i % 5) << 2;
        float4 v = make_float4(0.f, 0.f, 0.f, 0.f);
        if (e0 + e < E) v = *(const float4*)&r_feat[(size_t)(e0 + e) * NUM_GAUSS + q];
        Rs[e][q] = v.x; Rs[e][q+1] = v.y; Rs[e][q+2] = v.z; Rs[e][q+3] = v.w;
    }
    __syncthreads();

    const int em = tid >> 5;
    const int dn = (tid & 31) << 2;

    {
        float a1[8][4], aS[8][4];
        #pragma unroll
        for (int m = 0; m < 8; ++m)
            #pragma unroll
            for (int j = 0; j < 4; ++j) { a1[m][j] = 0.f; aS[m][j] = 0.f; }

        #pragma unroll 2
        for (int g = 0; g < 20; ++g) {
            float4 w1 = *(const float4*)&We1[g * OUT_DIM + dn];
            float4 wv = *(const float4*)&Wv[(148 + g) * OUT_DIM + dn];
            #pragma unroll
            for (int m = 0; m < 8; ++m) {
                float a = Rs[em * 8 + m][g];
                a1[m][0] = fmaf(a, w1.x, a1[m][0]); a1[m][1] = fmaf(a, w1.y, a1[m][1]);
                a1[m][2] = fmaf(a, w1.z, a1[m][2]); a1[m][3] = fmaf(a, w1.w, a1[m][3]);
                aS[m][0] = fmaf(a, wv.x, aS[m][0]); aS[m][1] = fmaf(a, wv.y, aS[m][1]);
                aS[m][2] = fmaf(a, wv.z, aS[m][2]); aS[m][3] = fmaf(a, wv.w, aS[m][3]);
            }
        }
        #pragma unroll
        for (int m = 0; m < 8; ++m) {
            int e = e0 + em * 8 + m;
            if (e < E) {
                float t0 = tanhf(a1[m][0]), t1 = tanhf(a1[m][1]);
                float t2 = tanhf(a1[m][2]), t3 = tanhf(a1[m][3]);
                *(float4*)&EA1[(size_t)e * OUT_DIM + dn] = make_float4(t0, t1, t2, t3);
                *(float4*)&ERV[(size_t)e * OUT_DIM + dn] =
                    make_float4(t0 * aS[m][0], t1 * aS[m][1], t2 * aS[m][2], t3 * aS[m][3]);
            }
        }
    }

    {
        float aR[8][4];
        #pragma unroll
        for (int m = 0; m < 8; ++m)
            #pragma unroll
            for (int j = 0; j < 4; ++j) aR[m][j] = 0.f;

        #pragma unroll 2
        for (int g = 0; g < 20; ++g) {
            float4 wk = *(const float4*)&Wk[(148 + g) * OUT_DIM + dn];
            #pragma unroll
            for (int m = 0; m < 8; ++m) {
                float a = Rs[em * 8 + m][g];
                aR[m][0] = fmaf(a, wk.x, aR[m][0]); aR[m][1] = fmaf(a, wk.y, aR[m][1]);
                aR[m][2] = fmaf(a, wk.z, aR[m][2]); aR[m][3] = fmaf(a, wk.w, aR[m][3]);
            }
        }
        const int hh = (tid & 31) >> 1;
        #pragma unroll
        for (int m = 0; m < 8; ++m) {
            int e = e0 + em * 8 + m;
            float s = 0.f;
            if (e < E) {
                float4 q = *(const float4*)&QE[(size_t)e * OUT_DIM + dn];  // L2-warm
                s = q.x*aR[m][0] + q.y*aR[m][1] + q.z*aR[m][2] + q.w*aR[m][3];
            }
            s += __shfl_xor(s, 1);
            if ((tid & 1) == 0 && e < E) QRK2[(size_t)e * NH + hh] = s;
        }
    }
}

// 2 segments per wave (R10-proven, ~50us): lane l = (sg = l>>5, s = l&31).
// Lane owns dims 4s..4s+3 of segment e = base + sg. Head h = s>>1 (a = s&1).
// KV rows are contiguous: kj = jj*12 + t (valid when T == E*12).
__global__ __launch_bounds__(256) void attn_wave_kernel(
    const float* __restrict__ pos,
    const int*   __restrict__ idx_i,
    const int*   __restrict__ idx_j,
    const int*   __restrict__ idx_k,
    const float* __restrict__ Wk,
    const float* __restrict__ Wv,
    const float* __restrict__ KB,
    const float* __restrict__ VB,
    const float* __restrict__ QE,
    const float* __restrict__ EA1,
    const float* __restrict__ ERV,
    const float* __restrict__ QRK2,
    float* __restrict__ out,
    int E)
{
    __shared__ float afL[WPB][2][12][13];

    // bijective XCD-aware swizzle (m204)
    unsigned bid = blockIdx.x, nwg = gridDim.x;
    unsigned qq = nwg >> 3, rr = nwg & 7, xc = bid & 7, rest = bid >> 3;
    unsigned swz = (xc < rr ? xc * (qq + 1) : rr * (qq + 1) + (xc - rr) * qq) + rest;

    const int l = threadIdx.x & 63;
    const int wvn = __builtin_amdgcn_readfirstlane(threadIdx.x >> 6);
    const int sg = l >> 5;          // which of the wave's 2 segments
    const int s  = l & 31;          // lane within segment
    const int e = (int)swz * (WPB * 2) + wvn * 2 + sg;
    if (e >= E) return;
    const int h = s >> 1;
    const int a = s & 1;
    const int d4 = 4 * s;           // dims d4..d4+3

    const int ii = idx_i[(size_t)e * 12];
    const int jj = idx_j[(size_t)e * 12];
    const size_t kjb = (size_t)jj * 12;   // contiguous KV block base row

    const float4 qe4  = *(const float4*)&QE [(size_t)e * OUT_DIM + d4];
    const float4 ea4  = *(const float4*)&EA1[(size_t)e * OUT_DIM + d4];
    const float4 erv4 = *(const float4*)&ERV[(size_t)e * OUT_DIM + d4];
    const float qrk2 = QRK2[(size_t)e * NH + h];

    // ---- triplet geometry (s < 12 lanes of each half) -> afL ----
    const float pix = pos[ii*3+0], piy = pos[ii*3+1], piz = pos[ii*3+2];
    const float jx = pos[jj*3+0]-pix, jy = pos[jj*3+1]-piy, jz = pos[jj*3+2]-piz;
    if (s < 12) {
        int kk = idx_k[(size_t)e * 12 + s];
        float kx = pos[kk*3+0]-pix, ky = pos[kk*3+1]-piy, kz = pos[kk*3+2]-piz;
        float aa = jx*kx + jy*ky + jz*kz;
        float cx = jy*kz - jz*ky, cy = jz*kx - jx*kz, cz = jx*ky - jy*kx;
        float bb = sqrtf(cx*cx + cy*cy + cz*cz);
        float ang = atan2f(bb, aa);
        float af0[13];
        af0[0] = ang;
        const float fr[6] = {1.f, 2.f, 3.f, 1.f, 0.5f, 1.f/3.f};
        #pragma unroll
        for (int q = 0; q < 6; ++q)
            __sincosf(ang * fr[q], &af0[1+q], &af0[7+q]);
        #pragma unroll
        for (int c = 0; c < 13; ++c) afL[wvn][sg][s][c] = af0[c];
    }

    // ---- qwk[c] = per-head dot8(QE, WkA[c]) : dot4 in-lane + 1 DPP ----
    float qwk[13];
    #pragma unroll
    for (int c = 0; c < 13; ++c) {
        float4 w = *(const float4*)&Wk[(168 + c) * OUT_DIM + d4];
        float p = qe4.x*w.x + qe4.y*w.y + qe4.z*w.z + qe4.w*w.w;
        p += __shfl_xor(p, 1);
        qwk[c] = p;
    }

    // ---- QK bond part for all 12 t; lane keeps t with (t&1)==a ----
    float qk6[6];
    #pragma unroll
    for (int t = 0; t < 12; ++t) {
        float4 kb = *(const float4*)&KB[(kjb + t) * OUT_DIM + d4];
        float v = qe4.x*kb.x + qe4.y*kb.y + qe4.z*kb.z + qe4.w*kb.w;
        v += __shfl_xor(v, 1);
        if ((t & 1) == a) qk6[t >> 1] = v;
    }

    wave_lds_fence();   // af ready

    // ---- angular part for own 6 t's + combine ----
    float lg[6];
    #pragma unroll
    for (int q = 0; q < 6; ++q) {
        int t = 2*q + a;
        float ang = 0.f;
        #pragma unroll
        for (int c = 0; c < 13; ++c) ang = fmaf(afL[wvn][sg][t][c], qwk[c], ang);
        lg[q] = (qk6[q] + ang + qrk2) * SCALE;
    }

    // ---- softmax over 12 within the 2-lane head group ----
    float m = lg[0];
    #pragma unroll
    for (int q = 1; q < 6; ++q) m = fmaxf(m, lg[q]);
    m = fmaxf(m, __shfl_xor(m, 1));
    float ex[6], ss = 0.f;
    #pragma unroll
    for (int q = 0; q < 6; ++q) { ex[q] = __expf(lg[q] - m); ss += ex[q]; }
    ss += __shfl_xor(ss, 1);
    float inv = 1.f / (ss + 1e-16f);
    float al[6], alp[6];
    #pragma unroll
    for (int q = 0; q < 6; ++q) { al[q] = ex[q] * inv; alp[q] = __shfl_xor(al[q], 1); }
    float Sh = ss * inv;

    // ---- waf[c] = sum_t alpha[t][h]*af[t][c] (own 6 t + 1 DPP) ----
    float waf[13];
    #pragma unroll
    for (int c = 0; c < 13; ++c) {
        float wp = 0.f;
        #pragma unroll
        for (int q = 0; q < 6; ++q) wp = fmaf(al[q], afL[wvn][sg][2*q + a][c], wp);
        wp += __shfl_xor(wp, 1);
        waf[c] = wp;
    }

    // ---- value accumulation over all 12 t (alpha via partner regs) ----
    float ac0 = 0.f, ac1 = 0.f, ac2 = 0.f, ac3 = 0.f;
    #pragma unroll
    for (int t = 0; t < 12; ++t) {
        float4 vb = *(const float4*)&VB[(kjb + t) * OUT_DIM + d4];
        float at = ((t & 1) == a) ? al[t >> 1] : alp[t >> 1];
        ac0 = fmaf(at, vb.x, ac0); ac1 = fmaf(at, vb.y, ac1);
        ac2 = fmaf(at, vb.z, ac2); ac3 = fmaf(at, vb.w, ac3);
    }

    // ---- angular value projection for this lane's 4 dims ----
    float vA0 = 0.f, vA1 = 0.f, vA2 = 0.f, vA3 = 0.f;
    #pragma unroll
    for (int c = 0; c < 13; ++c) {
        float4 w = *(const float4*)&Wv[(168 + c) * OUT_DIM + d4];
        vA0 = fmaf(waf[c], w.x, vA0); vA1 = fmaf(waf[c], w.y, vA1);
        vA2 = fmaf(waf[c], w.z, vA2); vA3 = fmaf(waf[c], w.w, vA3);
    }

    float4 o;
    o.x = ea4.x * (ac0 + vA0) + erv4.x * Sh;
    o.y = ea4.y * (ac1 + vA1) + erv4.y * Sh;
    o.z = ea4.z * (ac2 + vA2) + erv4.z * Sh;
    o.w = ea4.w * (ac3 + vA3) + erv4.w * Sh;
    *(float4*)&out[(size_t)e * OUT_DIM + d4] = o;
}

// ---------------- generic fallback (unused when T == E*12) ----------------
__global__ __launch_bounds__(128) void attn_generic_kernel(
    const float* __restrict__ pos,
    const int*   __restrict__ idx_i,
    const int*   __restrict__ idx_j,
    const int*   __restrict__ idx_k,
    const int*   __restrict__ idx_kj,
    const int*   __restrict__ idx_ji,
    const float* __restrict__ Wk,
    const float* __restrict__ Wv,
    const float* __restrict__ We1,
    const float* __restrict__ r_feat,
    const float* __restrict__ KB,
    const float* __restrict__ VB,
    const float* __restrict__ QE,
    float* __restrict__ out,
    int E, int T)
{
    __shared__ float rs[NUM_GAUSS];
    __shared__ float af[MAXT][13];
    __shared__ float logit[MAXT][NH];
    __shared__ float qwk[NH][13];
    __shared__ float waf[NH][13];
    __shared__ int   kjs[MAXT];
    __shared__ float qrk2s[NH];
    __shared__ float Shs[NH];

    const int e = blockIdx.x;
    const int d = threadIdx.x;
    const int h8 = d >> 3;

    int l = 0, hi = T;
    while (l < hi) { int mid = (l + hi) >> 1; if (idx_ji[mid] < e) l = mid + 1; else hi = mid; }
    int lo = l, c2 = 0;
    while (lo + c2 < T && c2 < MAXT && idx_ji[lo + c2] == e) ++c2;
    int cnt = c2;

    if (d < NUM_GAUSS) rs[d] = r_feat[(size_t)e * NUM_GAUSS + d];
    if (d < cnt) {
        int t = lo + d;
        kjs[d] = idx_kj[t];
        int ii = idx_i[t], jj = idx_j[t], kk = idx_k[t];
        float pix = pos[ii*3+0], piy = pos[ii*3+1], piz = pos[ii*3+2];
        float jx = pos[jj*3+0]-pix, jy = pos[jj*3+1]-piy, jz = pos[jj*3+2]-piz;
        float kx = pos[kk*3+0]-pix, ky = pos[kk*3+1]-piy, kz = pos[kk*3+2]-piz;
        float aa = jx*kx + jy*ky + jz*kz;
        float cx = jy*kz - jz*ky, cy = jz*kx - jx*kz, cz = jx*ky - jy*kx;
        float bb = sqrtf(cx*cx + cy*cy + cz*cz);
        float ang = atan2f(bb, aa);
        af[d][0] = ang;
        const float fr[6] = {1.f, 2.f, 3.f, 1.f, 0.5f, 1.f/3.f};
        #pragma unroll
        for (int q = 0; q < 6; ++q) {
            float s, cc;
            __sincosf(ang * fr[q], &s, &cc);
            af[d][1 + q] = s;
            af[d][7 + q] = cc;
        }
    }
    __syncthreads();

    const float qe = QE[(size_t)e * OUT_DIM + d];
    float s1 = 0.f, sk = 0.f, sv = 0.f;
    #pragma unroll
    for (int g = 0; g < NUM_GAUSS; ++g) {
        float rg = rs[g];
        s1 = fmaf(rg, We1[g * OUT_DIM + d], s1);
        sk = fmaf(rg, Wk[(148 + g) * OUT_DIM + d], sk);
        sv = fmaf(rg, Wv[(148 + g) * OUT_DIM + d], sv);
    }
    const float ea1 = tanhf(s1);
    const float rv2 = sv;

    {
        float v = qe * sk;
        v += __shfl_xor(v, 1, 8); v += __shfl_xor(v, 2, 8); v += __shfl_xor(v, 4, 8);
        if ((d & 7) == 0) qrk2s[h8] = v;
    }
    {
        float p[13];
        #pragma unroll
        for (int c = 0; c < 13; ++c) p[c] = qe * Wk[(168 + c) * OUT_DIM + d];
        #pragma unroll
        for (int c = 0; c < 13; ++c) {
            float v = p[c];
            v += __shfl_xor(v, 1, 8); v += __shfl_xor(v, 2, 8); v += __shfl_xor(v, 4, 8);
            if ((d & 7) == 0) qwk[h8][c] = v;
        }
    }
    for (int t = 0; t < cnt; ++t) {
        float lv = qe * KB[(size_t)kjs[t] * OUT_DIM + d];
        lv += __shfl_xor(lv, 1, 8); lv += __shfl_xor(lv, 2, 8); lv += __shfl_xor(lv, 4, 8);
        if ((d & 7) == 0) logit[t][h8] = lv;
    }
    __syncthreads();
    {
        const int hh = d & 15;
        for (int t = d >> 4; t < cnt; t += 8) {
            float s = 0.f;
            #pragma unroll
            for (int c = 0; c < 13; ++c) s = fmaf(af[t][c], qwk[hh][c], s);
            logit[t][hh] = (logit[t][hh] + s + qrk2s[hh]) * SCALE;
        }
    }
    __syncthreads();
    if (d < NH) {
        float m = -1e30f;
        for (int t = 0; t < cnt; ++t) m = fmaxf(m, logit[t][d]);
        float s = 0.f;
        for (int t = 0; t < cnt; ++t) { float ex = __expf(logit[t][d] - m); logit[t][d] = ex; s += ex; }
        float inv = 1.f / (s + 1e-16f);
        for (int t = 0; t < cnt; ++t) logit[t][d] *= inv;
        Shs[d] = s * inv;
    }
    __syncthreads();
    {
        const int hh = d & 15;
        int c = d >> 4;
        float w1 = 0.f;
        for (int t = 0; t < cnt; ++t) w1 = fmaf(logit[t][hh], af[t][c], w1);
        waf[hh][c] = w1;
        c += 8;
        if (c < 13) {
            float w2 = 0.f;
            for (int t = 0; t < cnt; ++t) w2 = fmaf(logit[t][hh], af[t][c], w2);
            waf[hh][c] = w2;
        }
    }
    __syncthreads();
    float vA = 0.f;
    #pragma unroll
    for (int c = 0; c < 13; ++c) vA = fmaf(waf[h8][c], Wv[(168 + c) * OUT_DIM + d], vA);
    float acc = 0.f;
    for (int t = 0; t < cnt; ++t)
        acc = fmaf(logit[t][h8], VB[(size_t)kjs[t] * OUT_DIM + d], acc);
    out[(size_t)e * OUT_DIM + d] = ea1 * (acc + vA + rv2 * Shs[h8]);
}

extern "C" void kernel_launch(void* const* d_in, const int* in_sizes, int n_in,
                              void* d_out, int out_size, void* d_ws, size_t ws_size,
                              hipStream_t stream) {
    const float* h_bond = (const float*)d_in[1];
    const float* pos    = (const float*)d_in[2];
    const int*   bidx   = (const int*)d_in[3];
    const int*   idx_i  = (const int*)d_in[4];
    const int*   idx_j  = (const int*)d_in[5];
    const int*   idx_k  = (const int*)d_in[6];
    const int*   idx_kj = (const int*)d_in[7];
    const int*   idx_ji = (const int*)d_in[8];
    const float* Wk     = (const float*)d_in[9];
    const float* Wv     = (const float*)d_in[10];
    const float* Wq     = (const float*)d_in[11];
    const float* We0    = (const float*)d_in[12];
    const float* We1    = (const float*)d_in[13];

    const int E = in_sizes[1] / INPUT_DIM;
    const int T = in_sizes[4];

    float* ws = (float*)d_ws;
    float* r_feat = ws;                               // E*20
    float* KB   = r_feat + (size_t)E * NUM_GAUSS;     // E*128
    float* VB   = KB   + (size_t)E * OUT_DIM;         // E*128
    float* QE   = VB   + (size_t)E * OUT_DIM;         // E*128
    float* EA1  = QE   + (size_t)E * OUT_DIM;         // E*128
    float* ERV  = EA1  + (size_t)E * OUT_DIM;         // E*128
    float* QRK2 = ERV  + (size_t)E * OUT_DIM;         // E*16

    bond_proj_kernel<<<(E + BM - 1) / BM, 256, 0, stream>>>(
        h_bond, pos, bidx, Wk, Wv, Wq, We0, r_feat, KB, VB, QE, E);

    redge_kernel<<<(E + BM - 1) / BM, 256, 0, stream>>>(
        r_feat, QE, Wk, Wv, We1, EA1, ERV, QRK2, E);

    if (T == E * 12) {
        const int segs_per_block = WPB * 2;
        attn_wave_kernel<<<(E + segs_per_block - 1) / segs_per_block, 64 * WPB, 0, stream>>>(
            pos, idx_i, idx_j, idx_k,
            Wk, Wv, KB, VB, QE, EA1, ERV, QRK2, (float*)d_out, E);
    } else {
        attn_generic_kernel<<<E, 128, 0, stream>>>(
            pos, idx_i, idx_j, idx_k, idx_kj, idx_ji,
            Wk, Wv, We1, r_feat, KB, VB, QE, (float*)d_out, E, T);
    }
}